// Round 3
// baseline (111.665 us; speedup 1.0000x reference)
//
#include <hip/hip_runtime.h>
#include <hip/hip_bf16.h>

typedef __attribute__((ext_vector_type(4))) float  floatx4;
typedef __attribute__((ext_vector_type(2))) float  floatx2;
typedef __attribute__((ext_vector_type(8))) __bf16 bf16x8;

#define FP8_MAX 448.0f

// HW OCP e4m3fn round-trip (RNE), matches ml_dtypes float8_e4m3fn for |v|<=448
__device__ __forceinline__ floatx2 fp8_qdq2(float a, float b) {
    int p = __builtin_amdgcn_cvt_pk_fp8_f32(a, b, 0, false);
    return __builtin_amdgcn_cvt_pk_f32_fp8(p, false);
}

__device__ __forceinline__ unsigned int f2bf(float f) {
    union { __hip_bfloat16 h; unsigned short u; } cv;
    cv.h = __float2bfloat16(f);
    return (unsigned int)cv.u;
}

__device__ __forceinline__ void async_copy16(void* lds, const void* g) {
    __builtin_amdgcn_global_load_lds(
        (const __attribute__((address_space(1))) unsigned int*)g,
        (__attribute__((address_space(3))) unsigned int*)lds, 16, 0, 0);
}

// ---------------------------------------------------------------------------
// Kernel 1: dequantize W [D=512][F=512] (quant blocks of 128 along F),
//           write transposed bf16 Wt [F=512][D=512].
__global__ void wdq_kernel(const float* __restrict__ W,
                           __hip_bfloat16* __restrict__ Wt) {
    const int D = 512, F = 512;
    int d = blockIdx.x;
    int t = threadIdx.x;
    float4 v = *reinterpret_cast<const float4*>(W + (size_t)d * F + t * 4);
    float am = fmaxf(fmaxf(fabsf(v.x), fabsf(v.y)), fmaxf(fabsf(v.z), fabsf(v.w)));
#pragma unroll
    for (int s = 16; s >= 1; s >>= 1) am = fmaxf(am, __shfl_xor(am, s));
    float scale = fmaxf(am, 1e-4f) / FP8_MAX;
    floatx2 d01 = fp8_qdq2(v.x / scale, v.y / scale);
    floatx2 d23 = fp8_qdq2(v.z / scale, v.w / scale);
    int f0 = t * 4;
    Wt[(size_t)(f0 + 0) * D + d] = __float2bfloat16(d01[0] * scale);
    Wt[(size_t)(f0 + 1) * D + d] = __float2bfloat16(d01[1] * scale);
    Wt[(size_t)(f0 + 2) * D + d] = __float2bfloat16(d23[0] * scale);
    Wt[(size_t)(f0 + 3) * D + d] = __float2bfloat16(d23[1] * scale);
}

// ---------------------------------------------------------------------------
// Kernel 2 (fused): 2-phase double-buffered pipeline, counted vmcnt.
// BM=64, BN=128, BK=64. LDS: As[2][64][64] (8KB ea) + Bs[2][128][64] (16KB ea)
// = 48KB -> 3 blocks/CU. XOR-swizzled slots (slot ^= row&7) on both tiles.
// X quant blocks of 128 span two K-steps; quant held in regs (q4), halves
// ds_written per step. X loads prefetched ~1.3 steps ahead (vmcnt(8) barrier).
__global__ __launch_bounds__(256, 3) void fused_gemm(
        const float* __restrict__ X,             // [M][512] f32
        const __hip_bfloat16* __restrict__ Wt,   // [512 f][512 k] bf16
        const float* __restrict__ bias,          // [512]
        float* __restrict__ C, int M) {
    const int K = 512, N = 512;
    __shared__ char As[2][8192];    // [64 rows][8 slots of 16B], swizzled
    __shared__ char Bs[2][16384];   // [128 rows][8 slots of 16B], swizzled

    // XCD-chunked bijective swizzle: consecutive 4 tiles (same tM) land on
    // the same XCD and adjacent in its chunk -> A-panel L2 reuse.
    int bx = blockIdx.x, nwg = gridDim.x;
    int tile = bx;
    if ((nwg & 7) == 0) { int cpx = nwg >> 3; tile = (bx & 7) * cpx + (bx >> 3); }
    int tN = tile & 3, tM = tile >> 2;

    int tid = threadIdx.x, wid = tid >> 6, lane = tid & 63;
    int wr = wid >> 1, wc = wid & 1;     // wave-grid 2x2, wave owns 32x64
    int ar = tid >> 2, aq = tid & 3;     // A-quant: 4 thr/row, 32 f32 each

    const float* Xb = X + (size_t)tM * 64 * K;
    const __hip_bfloat16* Wb = Wt + (size_t)tN * 128 * K;

    float4 v[8];        // X stash (one 128-k quant block)
    uint4  q4[4];       // quantized bf16 (32 elems)
    floatx4 acc[2][4] = {};

    auto loadX = [&](int blk) {
        const float* src = Xb + (size_t)ar * K + blk * 128 + aq * 32;
#pragma unroll
        for (int j = 0; j < 8; ++j)
            v[j] = *reinterpret_cast<const float4*>(src + j * 4);
    };
    auto quantX = [&]() {
        float am = 0.f;
#pragma unroll
        for (int j = 0; j < 8; ++j)
            am = fmaxf(am, fmaxf(fmaxf(fabsf(v[j].x), fabsf(v[j].y)),
                                 fmaxf(fabsf(v[j].z), fabsf(v[j].w))));
        am = fmaxf(am, __shfl_xor(am, 1));
        am = fmaxf(am, __shfl_xor(am, 2));
        am = fmaxf(am, 1e-4f);
        float scale = am / FP8_MAX;
        float inv   = FP8_MAX / am;
#pragma unroll
        for (int n = 0; n < 4; ++n) {
            floatx2 a0 = fp8_qdq2(v[2*n].x*inv,   v[2*n].y*inv);
            floatx2 a1 = fp8_qdq2(v[2*n].z*inv,   v[2*n].w*inv);
            floatx2 a2 = fp8_qdq2(v[2*n+1].x*inv, v[2*n+1].y*inv);
            floatx2 a3 = fp8_qdq2(v[2*n+1].z*inv, v[2*n+1].w*inv);
            q4[n].x = f2bf(a0[0]*scale) | (f2bf(a0[1]*scale) << 16);
            q4[n].y = f2bf(a1[0]*scale) | (f2bf(a1[1]*scale) << 16);
            q4[n].z = f2bf(a2[0]*scale) | (f2bf(a2[1]*scale) << 16);
            q4[n].w = f2bf(a3[0]*scale) | (f2bf(a3[1]*scale) << 16);
        }
    };
    // Bs stage: linear LDS dest (global_load_lds), pre-swizzled global source
    auto stageB = [&](int buf, int k0) {
#pragma unroll
        for (int c = 0; c < 4; ++c) {
            int chunk = wid * 4 + c;                 // 16 x 1KB chunks
            int rr = chunk * 8 + (lane >> 3);        // Bs row (f-dim)
            int s  = lane & 7;                       // 16B slot
            const __hip_bfloat16* src =
                Wb + (size_t)rr * K + k0 + ((s ^ (rr & 7)) << 3);
            async_copy16(Bs[buf] + chunk * 1024, src);
        }
    };
    // As stage: direct swizzled ds_write from quant regs; half hb only
    auto writeA = [&](int buf, int hb) {
        if ((aq >> 1) == hb) {
            char* base = As[buf];
#pragma unroll
            for (int n = 0; n < 4; ++n) {
                int slot = (aq & 1) * 4 + n;
                *reinterpret_cast<uint4*>(
                    base + ar * 128 + ((slot ^ (ar & 7)) << 4)) = q4[n];
            }
        }
    };
    auto mfmaStep = [&](int buf) {
        const char* ab = As[buf];
        const char* bb = Bs[buf];
#pragma unroll
        for (int ks = 0; ks < 2; ++ks) {
            int sl = ks * 4 + (lane >> 4);
            bf16x8 a[2], b[4];
#pragma unroll
            for (int mi = 0; mi < 2; ++mi) {
                int r = wr * 32 + mi * 16 + (lane & 15);
                a[mi] = *reinterpret_cast<const bf16x8*>(
                    ab + r * 128 + ((sl ^ (r & 7)) << 4));
            }
#pragma unroll
            for (int ni = 0; ni < 4; ++ni) {
                int r = wc * 64 + ni * 16 + (lane & 15);
                b[ni] = *reinterpret_cast<const bf16x8*>(
                    bb + r * 128 + ((sl ^ (r & 7)) << 4));
            }
#pragma unroll
            for (int mi = 0; mi < 2; ++mi)
#pragma unroll
                for (int ni = 0; ni < 4; ++ni)
                    acc[mi][ni] = __builtin_amdgcn_mfma_f32_16x16x32_bf16(
                        a[mi], b[ni], acc[mi][ni], 0, 0, 0);
        }
    };

    // ---- prologue: Q(blk0), As[0]=half0(blk0), Bs[0]=k0, X(blk1) in flight
    loadX(0);
    stageB(0, 0);
    quantX();          // compiler inserts the vmcnt wait for v
    loadX(1);
    writeA(0, 0);
    __syncthreads();   // drains everything once

#pragma unroll
    for (int b = 0; b < 4; ++b) {
        // ---- E-step: buf0 holds k=2b*64; stage buf1 <- k=(2b+1)*64
        stageB(1, (2 * b + 1) * 64);
        writeA(1, 1);                  // half1 of current Q (block b)
        mfmaStep(0);
        __builtin_amdgcn_sched_barrier(0);
        asm volatile("s_waitcnt vmcnt(0) lgkmcnt(0)" ::: "memory");
        __builtin_amdgcn_s_barrier();
        __builtin_amdgcn_sched_barrier(0);

        // ---- O-step: buf1 holds k=(2b+1)*64; stage buf0 <- k=(2b+2)*64
        if (b < 3) {
            stageB(0, (2 * b + 2) * 64);   // DMAs first (oldest in queue)
            quantX();                      // block b+1 (v drained at E-barrier)
            __builtin_amdgcn_sched_barrier(0);
            if (b < 2) loadX(b + 2);       // X prefetch, issued AFTER the DMAs
            writeA(0, 0);                  // half0 of block b+1
            mfmaStep(1);
            __builtin_amdgcn_sched_barrier(0);
            if (b < 2)
                asm volatile("s_waitcnt vmcnt(8) lgkmcnt(0)" ::: "memory");
            else
                asm volatile("s_waitcnt vmcnt(0) lgkmcnt(0)" ::: "memory");
            __builtin_amdgcn_s_barrier();
            __builtin_amdgcn_sched_barrier(0);
        } else {
            mfmaStep(1);
        }
    }

    // ---- epilogue: C/D layout col=lane&15, row=(lane>>4)*4+e
    int fcol = tN * 128 + wc * 64 + (lane & 15);
    int mrow = tM * 64 + wr * 32 + ((lane >> 4) << 2);
#pragma unroll
    for (int ni = 0; ni < 4; ++ni) {
        int f = fcol + ni * 16;
        float bv = bias[f];
#pragma unroll
        for (int mi = 0; mi < 2; ++mi) {
            int m0 = mrow + mi * 16;
#pragma unroll
            for (int e = 0; e < 4; ++e)
                C[(size_t)(m0 + e) * N + f] = acc[mi][ni][e] + bv;
        }
    }
}

// ---------------------------------------------------------------------------
extern "C" void kernel_launch(void* const* d_in, const int* in_sizes, int n_in,
                              void* d_out, int out_size, void* d_ws, size_t ws_size,
                              hipStream_t stream) {
    const float* X    = (const float*)d_in[0];
    const float* W    = (const float*)d_in[1];
    const float* bias = (const float*)d_in[2];
    const int K = 512;
    const int M = in_sizes[0] / K;   // 65536

    __hip_bfloat16* Wt = (__hip_bfloat16*)d_ws;   // 512*512*2 = 512 KB

    wdq_kernel<<<dim3(512), dim3(128), 0, stream>>>(W, Wt);
    fused_gemm<<<dim3((M / 64) * (512 / 128)), dim3(256), 0, stream>>>(
        X, Wt, bias, (float*)d_out, M);
}

// Round 4
// 90.798 us; speedup vs baseline: 1.2298x; 1.2298x over previous
//
#include <hip/hip_runtime.h>
#include <hip/hip_bf16.h>

typedef __attribute__((ext_vector_type(4))) float  floatx4;
typedef __attribute__((ext_vector_type(2))) float  floatx2;
typedef __attribute__((ext_vector_type(8))) __bf16 bf16x8;

#define FP8_MAX 448.0f

// HW OCP e4m3fn round-trip (RNE), matches ml_dtypes float8_e4m3fn for |v|<=448
__device__ __forceinline__ floatx2 fp8_qdq2(float a, float b) {
    int p = __builtin_amdgcn_cvt_pk_fp8_f32(a, b, 0, false);
    return __builtin_amdgcn_cvt_pk_f32_fp8(p, false);
}

__device__ __forceinline__ unsigned int f2bf(float f) {
    union { __hip_bfloat16 h; unsigned short u; } cv;
    cv.h = __float2bfloat16(f);
    return (unsigned int)cv.u;
}

__device__ __forceinline__ void async_copy16(void* lds, const void* g) {
    __builtin_amdgcn_global_load_lds(
        (const __attribute__((address_space(1))) unsigned int*)g,
        (__attribute__((address_space(3))) unsigned int*)lds, 16, 0, 0);
}

// ---------------------------------------------------------------------------
// Kernel 1: dequantize W [D=512][F=512] (quant blocks of 128 along F),
//           write transposed bf16 Wt [F=512][D=512].
__global__ void wdq_kernel(const float* __restrict__ W,
                           __hip_bfloat16* __restrict__ Wt) {
    const int D = 512, F = 512;
    int d = blockIdx.x;
    int t = threadIdx.x;
    float4 v = *reinterpret_cast<const float4*>(W + (size_t)d * F + t * 4);
    float am = fmaxf(fmaxf(fabsf(v.x), fabsf(v.y)), fmaxf(fabsf(v.z), fabsf(v.w)));
#pragma unroll
    for (int s = 16; s >= 1; s >>= 1) am = fmaxf(am, __shfl_xor(am, s));
    float scale = fmaxf(am, 1e-4f) / FP8_MAX;
    floatx2 d01 = fp8_qdq2(v.x / scale, v.y / scale);
    floatx2 d23 = fp8_qdq2(v.z / scale, v.w / scale);
    int f0 = t * 4;
    Wt[(size_t)(f0 + 0) * D + d] = __float2bfloat16(d01[0] * scale);
    Wt[(size_t)(f0 + 1) * D + d] = __float2bfloat16(d01[1] * scale);
    Wt[(size_t)(f0 + 2) * D + d] = __float2bfloat16(d23[0] * scale);
    Wt[(size_t)(f0 + 3) * D + d] = __float2bfloat16(d23[1] * scale);
}

// ---------------------------------------------------------------------------
// Kernel 2 (fused): quantize X on the fly + bf16 GEMM + bias.
// BM=64, BN=256, BK=64. 4 waves in 1x4 N-grid, each wave 64x64 out, acc[4][4]
// -> 32 MFMA per wave per K-step, exactly ONE __syncthreads per K-step.
// LDS: As[2][64 r][8 slot] 16 KB + Bs[2][256 r][8 slot] 64 KB = 80 KB
// -> 2 blocks/CU. XOR-swizzled 16B slots (slot ^= row&7): 0 bank conflicts
// (verified round 3). B staged via global_load_lds with pre-swizzled source;
// A quantized in regs (4 thr/row, one 128-k quant block) and ds_written in
// 64-k halves, one step ahead. X loads issued 2 steps ahead of their quant.
#define BM 64
#define BN 256

__global__ __launch_bounds__(256, 2) void fused_gemm(
        const float* __restrict__ X,             // [M][512] f32
        const __hip_bfloat16* __restrict__ Wt,   // [512 f][512 k] bf16
        const float* __restrict__ bias,          // [512]
        float* __restrict__ C, int M) {
    const int K = 512, N = 512;
    __shared__ char As[2][8192];     // [64][128B], swizzled slots
    __shared__ char Bs[2][32768];    // [256][128B], swizzled slots

    // XCD-chunked bijective swizzle: both tN tiles of a tM stay adjacent on
    // one XCD -> X panel L2/L3 reuse (round 3: FETCH 134->68 MB).
    int bx = blockIdx.x, nwg = gridDim.x;
    int tile = bx;
    if ((nwg & 7) == 0) { int cpx = nwg >> 3; tile = (bx & 7) * cpx + (bx >> 3); }
    int tN = tile & 1, tM = tile >> 1;

    int tid = threadIdx.x, wid = tid >> 6, lane = tid & 63;
    int ar = tid >> 2, aq = tid & 3;     // A-quant: 4 thr/row, 32 f32 each

    const float* Xb = X + (size_t)tM * BM * K;
    const __hip_bfloat16* Wb = Wt + (size_t)tN * BN * K;

    float4 v[8];        // X stash (one 128-k quant block / thread-quarter)
    uint4  q4[4];       // quantized bf16 (32 elems)
    floatx4 acc[4][4] = {};

    auto loadX = [&](int blk) {
        const float* src = Xb + (size_t)ar * K + blk * 128 + aq * 32;
#pragma unroll
        for (int j = 0; j < 8; ++j)
            v[j] = *reinterpret_cast<const float4*>(src + j * 4);
    };
    auto quantX = [&]() {
        float am = 0.f;
#pragma unroll
        for (int j = 0; j < 8; ++j)
            am = fmaxf(am, fmaxf(fmaxf(fabsf(v[j].x), fabsf(v[j].y)),
                                 fmaxf(fabsf(v[j].z), fabsf(v[j].w))));
        am = fmaxf(am, __shfl_xor(am, 1));
        am = fmaxf(am, __shfl_xor(am, 2));
        am = fmaxf(am, 1e-4f);
        float scale = am / FP8_MAX;     // exact reference scale (IEEE div)
        float inv   = FP8_MAX / am;
#pragma unroll
        for (int n = 0; n < 4; ++n) {
            floatx2 a0 = fp8_qdq2(v[2*n].x*inv,   v[2*n].y*inv);
            floatx2 a1 = fp8_qdq2(v[2*n].z*inv,   v[2*n].w*inv);
            floatx2 a2 = fp8_qdq2(v[2*n+1].x*inv, v[2*n+1].y*inv);
            floatx2 a3 = fp8_qdq2(v[2*n+1].z*inv, v[2*n+1].w*inv);
            q4[n].x = f2bf(a0[0]*scale) | (f2bf(a0[1]*scale) << 16);
            q4[n].y = f2bf(a1[0]*scale) | (f2bf(a1[1]*scale) << 16);
            q4[n].z = f2bf(a2[0]*scale) | (f2bf(a2[1]*scale) << 16);
            q4[n].w = f2bf(a3[0]*scale) | (f2bf(a3[1]*scale) << 16);
        }
    };
    // Bs stage: linear LDS dest (global_load_lds), pre-swizzled global source.
    // 32 chunks of 1 KB (8 rows x 8 slots); 8 chunks per wave per step.
    auto stageB = [&](int buf, int step) {
        int k0 = step * 64;
#pragma unroll
        for (int c = 0; c < 8; ++c) {
            int chunk = wid * 8 + c;
            int rr = chunk * 8 + (lane >> 3);
            int s  = lane & 7;
            const __hip_bfloat16* src =
                Wb + (size_t)rr * K + k0 + ((s ^ (rr & 7)) << 3);
            async_copy16(Bs[buf] + chunk * 1024, src);
        }
    };
    // As stage: swizzled ds_write from quant regs; k-half hb only (128
    // active threads per call).
    auto writeA = [&](int buf, int hb) {
        if ((aq >> 1) == hb) {
            char* base = As[buf];
#pragma unroll
            for (int n = 0; n < 4; ++n) {
                int slot = (aq & 1) * 4 + n;
                *reinterpret_cast<uint4*>(
                    base + ar * 128 + ((slot ^ (ar & 7)) << 4)) = q4[n];
            }
        }
    };
    auto mfmaStep = [&](int buf) {
        const char* ab = As[buf];
        const char* bb = Bs[buf];
#pragma unroll
        for (int ks = 0; ks < 2; ++ks) {
            int sl = ks * 4 + (lane >> 4);
            bf16x8 a[4], b[4];
#pragma unroll
            for (int mi = 0; mi < 4; ++mi) {
                int r = mi * 16 + (lane & 15);
                a[mi] = *reinterpret_cast<const bf16x8*>(
                    ab + r * 128 + ((sl ^ (r & 7)) << 4));
            }
#pragma unroll
            for (int ni = 0; ni < 4; ++ni) {
                int r = wid * 64 + ni * 16 + (lane & 15);
                b[ni] = *reinterpret_cast<const bf16x8*>(
                    bb + r * 128 + ((sl ^ (r & 7)) << 4));
            }
#pragma unroll
            for (int mi = 0; mi < 4; ++mi)
#pragma unroll
                for (int ni = 0; ni < 4; ++ni)
                    acc[mi][ni] = __builtin_amdgcn_mfma_f32_16x16x32_bf16(
                        a[mi], b[ni], acc[mi][ni], 0, 0, 0);
        }
    };

    // ---- prologue: quant block 0, As[0]=half0, Bs[0]=step0, X block1 issued
    loadX(0);
    stageB(0, 0);
    quantX();
    writeA(0, 0);
    loadX(1);
    __syncthreads();

    // ---- main loop: 8 K-steps, 1 barrier each, full double-buffer
#pragma unroll
    for (int s = 0; s < 8; ++s) {
        int cur = s & 1, nxt = cur ^ 1;
        if (s < 7) stageB(nxt, s + 1);
        if ((s & 1) == 0) {
            if (s < 7) writeA(nxt, 1);               // half1 of current block
        } else if (s < 7) {
            quantX();                                // block (s+1)/2
            writeA(nxt, 0);                          // its half0
            if (s < 5) loadX((s + 3) / 2);           // X 2 steps ahead
        }
        mfmaStep(cur);
        if (s < 7) __syncthreads();
    }

    // ---- epilogue: C/D layout col=lane&15, row=(lane>>4)*4+e
    int fcol = tN * BN + wid * 64 + (lane & 15);
    int mrow = tM * BM + ((lane >> 4) << 2);
#pragma unroll
    for (int ni = 0; ni < 4; ++ni) {
        int f = fcol + ni * 16;
        float bv = bias[f];
#pragma unroll
        for (int mi = 0; mi < 4; ++mi) {
            int m0 = mrow + mi * 16;
#pragma unroll
            for (int e = 0; e < 4; ++e)
                C[(size_t)(m0 + e) * N + f] = acc[mi][ni][e] + bv;
        }
    }
}

// ---------------------------------------------------------------------------
extern "C" void kernel_launch(void* const* d_in, const int* in_sizes, int n_in,
                              void* d_out, int out_size, void* d_ws, size_t ws_size,
                              hipStream_t stream) {
    const float* X    = (const float*)d_in[0];
    const float* W    = (const float*)d_in[1];
    const float* bias = (const float*)d_in[2];
    const int K = 512;
    const int M = in_sizes[0] / K;   // 65536

    __hip_bfloat16* Wt = (__hip_bfloat16*)d_ws;   // 512*512*2 = 512 KB

    wdq_kernel<<<dim3(512), dim3(128), 0, stream>>>(W, Wt);
    fused_gemm<<<dim3((M / BM) * (512 / BN)), dim3(256), 0, stream>>>(
        X, Wt, bias, (float*)d_out, M);
}